// Round 3
// baseline (877.022 us; speedup 1.0000x reference)
//
#include <hip/hip_runtime.h>
#include <hip/hip_bf16.h>

// out[m,n] = sum_r sum_k inp[r,m,k] * wgt[r,n,k]
// W=8, M=N=4096, K=1792 -> single GEMM M=N=4096, Ktot=14336, fp32 in/out,
// bf16 MFMA (absmax 7.8e-3 vs 3.39e-2 threshold, R1/R2).
//
// R2 -> R3: XCD-aware block swizzle. R1 and R2 both saturated ~9 TB/s of
// L3 fetch (R1 7.3GB/811us, R2 3.67GB/417us) -> Infinity-Cache BW bound.
// Cluster each XCD's 32 blocks (b%8 round-robin) into a 4x8 rectangle of
// the 16x16 tile grid: per-XCD distinct bytes/iter 1MB -> 192KB; re-reads
// hit the XCD-local 4MB L2 (34.5 TB/s aggregate) instead of L3.

#define Wsz 8
#define Mdim 4096
#define Ndim 4096
#define Kshard 1792
#define KTOT 14336
#define LDSBUF 32768   // one pipeline stage: A 16KB + B 16KB

typedef __attribute__((ext_vector_type(8))) short short8;
typedef __attribute__((ext_vector_type(4))) float f32x4;

__device__ __forceinline__ unsigned short f2bf(float x) {
    unsigned u = __builtin_bit_cast(unsigned, x);
    u = (u + 0x7FFFu + ((u >> 16) & 1u)) >> 16;   // RNE
    return (unsigned short)u;
}

// ---------------------------------------------------------------------------
// Convert+reshuffle: src [8][4096][1792] f32 -> dst [4096][14336] bf16.
// ---------------------------------------------------------------------------
__global__ void __launch_bounds__(256) cvt_kernel(const float* __restrict__ src,
                                                  unsigned short* __restrict__ dst) {
    unsigned g = blockIdx.x * 256 + threadIdx.x;   // < 7,340,032
    unsigned k8 = g % 224u;
    unsigned t  = g / 224u;
    unsigned m  = t & 4095u;
    unsigned r  = t >> 12;
    const float4* p = (const float4*)(src + ((size_t)r * Mdim * Kshard + (size_t)m * Kshard + k8 * 8));
    float4 v0 = p[0], v1 = p[1];
    uint4 o;
    o.x = (unsigned)f2bf(v0.x) | ((unsigned)f2bf(v0.y) << 16);
    o.y = (unsigned)f2bf(v0.z) | ((unsigned)f2bf(v0.w) << 16);
    o.z = (unsigned)f2bf(v1.x) | ((unsigned)f2bf(v1.y) << 16);
    o.w = (unsigned)f2bf(v1.z) | ((unsigned)f2bf(v1.w) << 16);
    *(uint4*)(dst + ((size_t)m * KTOT + (size_t)r * Kshard + k8 * 8)) = o;
}

// ---------------------------------------------------------------------------
// 256x256 tile GEMM, BK=32, 512 threads (8 waves as 4Mx2N, wave = 64x128).
// Depth-2 pipeline over 4 LDS buffers; raw s_waitcnt vmcnt(4)+s_barrier.
// LDS 16B-chunk XOR swizzle on the global-address side (bank-conflict-free,
// verified 0 conflicts in R2). XCD-clustered tile mapping (R3).
// ---------------------------------------------------------------------------
__global__ void __launch_bounds__(512, 2) gemm_bt(const unsigned short* __restrict__ A,
                                                  const unsigned short* __restrict__ B,
                                                  float* __restrict__ C) {
    extern __shared__ char smem[];   // 4 * LDSBUF = 128 KiB

    const int tid = threadIdx.x;
    const int w = tid >> 6, lane = tid & 63;
    const int l15 = lane & 15, quad = lane >> 4;
    const int wm = (w >> 1) * 64;    // wave M offset (0..192)
    const int wn = (w & 1) * 128;    // wave N offset (0/128)

    // --- XCD-aware swizzle: XCD x (= b%8, dispatch round-robin) owns the
    // 4x8 tile rectangle [ (x>>1)*4 .. +4 ) x ( (x&1)*8 .. +8 ).
    const int b = blockIdx.y * 16 + blockIdx.x;   // 0..255
    const int x = b & 7, i = b >> 3;              // i in [0,32)
    const int ty = (x >> 1) * 4 + (i >> 3);
    const int tx = (x & 1) * 8 + (i & 7);
    const long bm = (long)ty * 256, bn = (long)tx * 256;

    // --- staging decode: 512 lanes cover 512 of 1024 16B chunks per matrix;
    // each thread issues chunk g and g+512 (rows sr and sr+128).
    // Global k-chunk for (row r, col c) is q = c ^ ((r>>1)&3).
    const int chunk = w * 64 + lane;          // 0..511
    const int sr = chunk >> 2;                // 0..127
    const int sq = (chunk & 3) ^ ((sr >> 1) & 3);
    const unsigned short* aP0 = A + (size_t)(bm + sr) * KTOT + sq * 8;
    const unsigned short* aP1 = aP0 + (size_t)128 * KTOT;
    const unsigned short* bP0 = B + (size_t)(bn + sr) * KTOT + sq * 8;
    const unsigned short* bP1 = bP0 + (size_t)128 * KTOT;
    const int ldsW = w * 1024;                // wave-uniform LDS base offset

    // --- fragment read offsets (row stride 64B, swizzled 16B column)
    const int swz = (quad ^ ((l15 >> 1) & 3)) * 16;
    const int aoff = (wm + l15) * 64 + swz;
    const int boff = 16384 + (wn + l15) * 64 + swz;

    f32x4 acc[4][8] = {};

#define STAGE(bufbase, kt)                                                                              \
    do {                                                                                                \
        __builtin_amdgcn_global_load_lds((const __attribute__((address_space(1))) void*)(aP0 + (kt)),   \
            (__attribute__((address_space(3))) void*)(smem + (bufbase) + ldsW), 16, 0, 0);              \
        __builtin_amdgcn_global_load_lds((const __attribute__((address_space(1))) void*)(aP1 + (kt)),   \
            (__attribute__((address_space(3))) void*)(smem + (bufbase) + ldsW + 8192), 16, 0, 0);       \
        __builtin_amdgcn_global_load_lds((const __attribute__((address_space(1))) void*)(bP0 + (kt)),   \
            (__attribute__((address_space(3))) void*)(smem + (bufbase) + 16384 + ldsW), 16, 0, 0);      \
        __builtin_amdgcn_global_load_lds((const __attribute__((address_space(1))) void*)(bP1 + (kt)),   \
            (__attribute__((address_space(3))) void*)(smem + (bufbase) + 16384 + ldsW + 8192), 16, 0, 0);\
    } while (0)

#define COMPUTE(bufbase)                                                                 \
    do {                                                                                 \
        short8 af[4], bfr[8];                                                            \
        _Pragma("unroll") for (int i2 = 0; i2 < 4; ++i2)                                 \
            af[i2] = *(const short8*)(smem + (bufbase) + aoff + i2 * 1024);              \
        _Pragma("unroll") for (int i2 = 0; i2 < 8; ++i2)                                 \
            bfr[i2] = *(const short8*)(smem + (bufbase) + boff + i2 * 1024);             \
        _Pragma("unroll") for (int mi = 0; mi < 4; ++mi)                                 \
            _Pragma("unroll") for (int ni = 0; ni < 8; ++ni)                             \
                acc[mi][ni] = __builtin_amdgcn_mfma_f32_16x16x32_bf16(af[mi], bfr[ni],   \
                                                                      acc[mi][ni], 0, 0, 0); \
    } while (0)

#define PIPE_BAR4() asm volatile("s_waitcnt vmcnt(4)\ns_barrier" ::: "memory")
#define PIPE_BAR0() asm volatile("s_waitcnt vmcnt(0)\ns_barrier" ::: "memory")

    STAGE(0, 0);          // iter 0 -> buf 0
    STAGE(LDSBUF, 32);    // iter 1 -> buf 1

    long kt = 0;
    for (int blk = 0; blk < 111; ++blk) {
#pragma unroll
        for (int u = 0; u < 4; ++u) {
            PIPE_BAR4();                          // oldest 4 loads (this buf) done
            STAGE(((u + 2) & 3) * LDSBUF, kt + 64);
            COMPUTE(u * LDSBUF);
            kt += 32;
        }
    }
    // tail: iters 444..447 (kt = 14208)
    PIPE_BAR4(); STAGE(2 * LDSBUF, kt + 64); COMPUTE(0);          kt += 32;  // 444
    PIPE_BAR4(); STAGE(3 * LDSBUF, kt + 64); COMPUTE(LDSBUF);     kt += 32;  // 445
    PIPE_BAR4();                             COMPUTE(2 * LDSBUF);            // 446
    PIPE_BAR0();                             COMPUTE(3 * LDSBUF);            // 447

#undef STAGE
#undef COMPUTE
#undef PIPE_BAR4
#undef PIPE_BAR0

    // C/D layout (m89/m91): col = lane&15, row = quad*4 + reg
#pragma unroll
    for (int mi = 0; mi < 4; ++mi)
#pragma unroll
        for (int ni = 0; ni < 8; ++ni) {
            const long col = bn + wn + ni * 16 + l15;
#pragma unroll
            for (int r2 = 0; r2 < 4; ++r2) {
                const long row = bm + wm + mi * 16 + quad * 4 + r2;
                C[row * Ndim + col] = acc[mi][ni][r2];
            }
        }
}

// ---------------------------------------------------------------------------
// Fallback (ws too small): inline-convert 128x128 kernel.
// ---------------------------------------------------------------------------
__global__ void __launch_bounds__(256) gemm_inline(const float* __restrict__ A,
                                                   const float* __restrict__ B,
                                                   float* __restrict__ C) {
    __shared__ short As[128 * 32];
    __shared__ short Bs[128 * 32];

    const int tid = threadIdx.x;
    const int w = tid >> 6, lane = tid & 63;
    const int bm = blockIdx.y * 128, bn = blockIdx.x * 128;
    const int wm = (w >> 1) * 64, wn = (w & 1) * 64;
    const int lane15 = lane & 15, quad = lane >> 4;

    const int srow = tid >> 3;
    const int skc  = (tid & 7) * 4;

    const char* a_rd = (const char*)As + ((size_t)(wm + lane15) * 32 + quad * 8) * 2;
    const char* b_rd = (const char*)Bs + ((size_t)(wn + lane15) * 32 + quad * 8) * 2;

    f32x4 acc[4][4] = {};
    long base = 0; int kloc = 0;

    for (int kt = 0; kt < KTOT; kt += 32) {
        const float* ap = A + base + kloc + (long)(bm + srow) * Kshard + skc;
        const float* bp = B + base + kloc + (long)(bn + srow) * Kshard + skc;
        float4 av[4], bv[4];
#pragma unroll
        for (int i = 0; i < 4; ++i) {
            av[i] = *(const float4*)(ap + (long)i * 32 * Kshard);
            bv[i] = *(const float4*)(bp + (long)i * 32 * Kshard);
        }
        __syncthreads();
#pragma unroll
        for (int i = 0; i < 4; ++i) {
            ushort4 oa, ob;
            oa.x = f2bf(av[i].x); oa.y = f2bf(av[i].y); oa.z = f2bf(av[i].z); oa.w = f2bf(av[i].w);
            ob.x = f2bf(bv[i].x); ob.y = f2bf(bv[i].y); ob.z = f2bf(bv[i].z); ob.w = f2bf(bv[i].w);
            *(ushort4*)((char*)As + ((size_t)(srow + i * 32) * 32 + skc) * 2) = oa;
            *(ushort4*)((char*)Bs + ((size_t)(srow + i * 32) * 32 + skc) * 2) = ob;
        }
        __syncthreads();

        short8 af[4], bfr[4];
#pragma unroll
        for (int i = 0; i < 4; ++i) {
            af[i]  = *(const short8*)(a_rd + (size_t)i * 16 * 64);
            bfr[i] = *(const short8*)(b_rd + (size_t)i * 16 * 64);
        }
#pragma unroll
        for (int mi = 0; mi < 4; ++mi)
#pragma unroll
            for (int ni = 0; ni < 4; ++ni)
                acc[mi][ni] = __builtin_amdgcn_mfma_f32_16x16x32_bf16(af[mi], bfr[ni], acc[mi][ni], 0, 0, 0);

        kloc += 32;
        if (kloc == Kshard) { kloc = 0; base += (long)Mdim * Kshard; }
    }

#pragma unroll
    for (int mi = 0; mi < 4; ++mi)
#pragma unroll
        for (int ni = 0; ni < 4; ++ni) {
            const int col = bn + wn + ni * 16 + lane15;
#pragma unroll
            for (int r2 = 0; r2 < 4; ++r2) {
                const int row = bm + wm + mi * 16 + quad * 4 + r2;
                C[(size_t)row * Ndim + col] = acc[mi][ni][r2];
            }
        }
}

extern "C" void kernel_launch(void* const* d_in, const int* in_sizes, int n_in,
                              void* d_out, int out_size, void* d_ws, size_t ws_size,
                              hipStream_t stream) {
    const float* inp = (const float*)d_in[0];   // [8][4096][1792] f32
    const float* wgt = (const float*)d_in[1];   // [8][4096][1792] f32
    float* out = (float*)d_out;                 // [4096][4096] f32

    const size_t one_mat = (size_t)Mdim * KTOT * 2;   // 117,440,512 B
    if (ws_size >= 2 * one_mat) {
        unsigned short* Abf = (unsigned short*)d_ws;
        unsigned short* Bbf = (unsigned short*)((char*)d_ws + one_mat);
        const int cvt_blocks = (Wsz * Mdim * (Kshard / 8)) / 256;   // 28672
        cvt_kernel<<<cvt_blocks, 256, 0, stream>>>(inp, Abf);
        cvt_kernel<<<cvt_blocks, 256, 0, stream>>>(wgt, Bbf);
        hipFuncSetAttribute(reinterpret_cast<const void*>(gemm_bt),
                            hipFuncAttributeMaxDynamicSharedMemorySize, 4 * LDSBUF);
        dim3 grid(Ndim / 256, Mdim / 256);
        gemm_bt<<<grid, 512, 4 * LDSBUF, stream>>>(Abf, Bbf, out);
    } else {
        dim3 grid(Ndim / 128, Mdim / 128);
        gemm_inline<<<grid, 256, 0, stream>>>(inp, wgt, out);
    }
}